// Round 1
// baseline (284.019 us; speedup 1.0000x reference)
//
#include <hip/hip_runtime.h>
#include <cstdint>
#include <cstddef>

#define WS 64
#define SHIFT 32
#define WTOT 8192
#define NWIN 128
#define SCALE_F 0.125f

typedef __bf16 bf16x8 __attribute__((ext_vector_type(8)));
typedef float f32x4 __attribute__((ext_vector_type(4)));

__device__ __forceinline__ unsigned short f2bf(float f) {
  unsigned int u = __builtin_bit_cast(unsigned int, f);
  u += 0x7FFFu + ((u >> 16) & 1u);   // round-to-nearest-even
  return (unsigned short)(u >> 16);
}
__device__ __forceinline__ float bf2f(unsigned short h) {
  unsigned int u = ((unsigned int)h) << 16;
  return __builtin_bit_cast(float, u);
}

// One block (256 thr = 4 waves) per 64x64 window. 4096 blocks total.
__global__ __launch_bounds__(256, 3) void win_attn(
    const float* __restrict__ q, const float* __restrict__ k,
    const float* __restrict__ v, const float* __restrict__ table,
    float* __restrict__ xout, float* __restrict__ attn_out) {
  // hi/lo bf16 split buffers (emulated-fp32 MFMA). Q buffers are reused for P.
  __shared__ __align__(16) unsigned short s_qhi[WS * WS];  // later P_hi
  __shared__ __align__(16) unsigned short s_qlo[WS * WS];  // later P_lo
  __shared__ __align__(16) unsigned short s_khi[WS * WS];
  __shared__ __align__(16) unsigned short s_klo[WS * WS];
  __shared__ __align__(16) unsigned short s_vthi[WS * WS];  // V^T: [c][m]
  __shared__ __align__(16) unsigned short s_vtlo[WS * WS];
  __shared__ float s_bias[2 * WS - 1];

  const int t = threadIdx.x;
  const int b = blockIdx.x;           // window id 0..4095
  const int batch = b >> 7;
  const int win = b & (NWIN - 1);

  if (t < 2 * WS - 1) s_bias[t] = table[t];

  // ---------- load q,k,v (with cyclic shift) and convert to hi/lo bf16 ----------
  {
    const int lr = t >> 2;              // row 0..63
    const int lc = (t & 3) << 4;        // col base 0,16,32,48
    const int grow = (win * WS + lr + SHIFT) & (WTOT - 1);
    const size_t gbase = ((size_t)batch * WTOT + grow) * WS + lc;
#pragma unroll
    for (int i = 0; i < 16; i += 4) {
      const float4 qv = *(const float4*)(q + gbase + i);
      const float4 kv = *(const float4*)(k + gbase + i);
      const float4 vv = *(const float4*)(v + gbase + i);
      const float qa[4] = {qv.x, qv.y, qv.z, qv.w};
      const float ka[4] = {kv.x, kv.y, kv.z, kv.w};
      const float va[4] = {vv.x, vv.y, vv.z, vv.w};
#pragma unroll
      for (int e = 0; e < 4; ++e) {
        const int cc = lc + i + e;
        unsigned short h;
        h = f2bf(qa[e]);
        s_qhi[lr * WS + cc] = h;
        s_qlo[lr * WS + cc] = f2bf(qa[e] - bf2f(h));
        h = f2bf(ka[e]);
        s_khi[lr * WS + cc] = h;
        s_klo[lr * WS + cc] = f2bf(ka[e] - bf2f(h));
        h = f2bf(va[e]);
        s_vthi[cc * WS + lr] = h;                    // transposed store
        s_vtlo[cc * WS + lr] = f2bf(va[e] - bf2f(h));
      }
    }
  }
  __syncthreads();

  const int lane = t & 63;
  const int wave = t >> 6;       // 0..3 -> rows [16w,16w+16)
  const int lrow = lane & 15;    // A/B fragment row index
  const int quad = lane >> 4;    // 0..3

  // ---------- S = Q K^T via split-bf16 MFMA (3 mfma per K-half per tile) ----------
  const f32x4 z4 = {0.f, 0.f, 0.f, 0.f};
  f32x4 acc[4] = {z4, z4, z4, z4};   // col tiles j=0..3
#pragma unroll
  for (int kh = 0; kh < 2; ++kh) {
    const int k0 = kh * 32 + quad * 8;
    const bf16x8 ahi = *(const bf16x8*)(s_qhi + (wave * 16 + lrow) * WS + k0);
    const bf16x8 alo = *(const bf16x8*)(s_qlo + (wave * 16 + lrow) * WS + k0);
#pragma unroll
    for (int j = 0; j < 4; ++j) {
      const bf16x8 bhi = *(const bf16x8*)(s_khi + (j * 16 + lrow) * WS + k0);
      const bf16x8 blo = *(const bf16x8*)(s_klo + (j * 16 + lrow) * WS + k0);
      acc[j] = __builtin_amdgcn_mfma_f32_16x16x32_bf16(ahi, bhi, acc[j], 0, 0, 0);
      acc[j] = __builtin_amdgcn_mfma_f32_16x16x32_bf16(alo, bhi, acc[j], 0, 0, 0);
      acc[j] = __builtin_amdgcn_mfma_f32_16x16x32_bf16(ahi, blo, acc[j], 0, 0, 0);
    }
  }

  // ---------- scale + bias + shift-mask, then register softmax ----------
  // C/D layout: row r = wave*16 + quad*4 + reg, col m = j*16 + (lane&15).
  // A full S row = 16 lanes of one quad x 4 col-tiles -> shfl_xor(1,2,4,8).
  const bool masked = (win == NWIN - 1);
  float p[4][4];  // [reg][j]
#pragma unroll
  for (int reg = 0; reg < 4; ++reg) {
    const int r = wave * 16 + quad * 4 + reg;
    float val[4];
    float vmax = -1e30f;
#pragma unroll
    for (int j = 0; j < 4; ++j) {
      const int m = j * 16 + lrow;
      float s = acc[j][reg] * SCALE_F + s_bias[r - m + (WS - 1)];
      if (masked && (((r ^ m) & 32) != 0)) s -= 100.0f;
      val[j] = s;
      vmax = fmaxf(vmax, s);
    }
#pragma unroll
    for (int off = 1; off < 16; off <<= 1)
      vmax = fmaxf(vmax, __shfl_xor(vmax, off, 64));
    float sum = 0.f;
#pragma unroll
    for (int j = 0; j < 4; ++j) {
      val[j] = __expf(val[j] - vmax);
      sum += val[j];
    }
#pragma unroll
    for (int off = 1; off < 16; off <<= 1)
      sum += __shfl_xor(sum, off, 64);
    const float inv = 1.0f / sum;
#pragma unroll
    for (int j = 0; j < 4; ++j) p[reg][j] = val[j] * inv;
  }

  // ---------- write attn to global, stage P (hi/lo) into reused Q buffers ----------
  // Each wave reads/writes only its own 16-row slab of s_q*, so no barrier
  // needed before the overwrite (DS ops within a wave are ordered).
  {
    float* arow = attn_out + (size_t)b * (WS * WS);
#pragma unroll
    for (int reg = 0; reg < 4; ++reg) {
      const int r = wave * 16 + quad * 4 + reg;
#pragma unroll
      for (int j = 0; j < 4; ++j) {
        const int m = j * 16 + lrow;
        const float pv = p[reg][j];
        arow[r * WS + m] = pv;
        const unsigned short h = f2bf(pv);
        s_qhi[r * WS + m] = h;
        s_qlo[r * WS + m] = f2bf(pv - bf2f(h));
      }
    }
  }
  __syncthreads();  // cheap safety barrier before PV fragment reads

  // ---------- X = P V via split-bf16 MFMA ----------
  f32x4 xacc[4] = {z4, z4, z4, z4};
#pragma unroll
  for (int kh = 0; kh < 2; ++kh) {
    const int k0 = kh * 32 + quad * 8;
    const bf16x8 phi = *(const bf16x8*)(s_qhi + (wave * 16 + lrow) * WS + k0);
    const bf16x8 plo = *(const bf16x8*)(s_qlo + (wave * 16 + lrow) * WS + k0);
#pragma unroll
    for (int j = 0; j < 4; ++j) {
      const bf16x8 vhi = *(const bf16x8*)(s_vthi + (j * 16 + lrow) * WS + k0);
      const bf16x8 vlo = *(const bf16x8*)(s_vtlo + (j * 16 + lrow) * WS + k0);
      xacc[j] = __builtin_amdgcn_mfma_f32_16x16x32_bf16(phi, vhi, xacc[j], 0, 0, 0);
      xacc[j] = __builtin_amdgcn_mfma_f32_16x16x32_bf16(plo, vhi, xacc[j], 0, 0, 0);
      xacc[j] = __builtin_amdgcn_mfma_f32_16x16x32_bf16(phi, vlo, xacc[j], 0, 0, 0);
    }
  }

  // ---------- store x with reverse cyclic shift ----------
#pragma unroll
  for (int reg = 0; reg < 4; ++reg) {
    const int r = wave * 16 + quad * 4 + reg;
    const int gr = (win * WS + r + SHIFT) & (WTOT - 1);
    float* xrow = xout + ((size_t)batch * WTOT + gr) * WS;
#pragma unroll
    for (int j = 0; j < 4; ++j) {
      xrow[j * 16 + lrow] = xacc[j][reg];
    }
  }
}

extern "C" void kernel_launch(void* const* d_in, const int* in_sizes, int n_in,
                              void* d_out, int out_size, void* d_ws, size_t ws_size,
                              hipStream_t stream) {
  (void)in_sizes; (void)n_in; (void)out_size; (void)d_ws; (void)ws_size;
  const float* q = (const float*)d_in[0];
  const float* k = (const float*)d_in[1];
  const float* v = (const float*)d_in[2];
  const float* table = (const float*)d_in[3];
  float* xout = (float*)d_out;                                  // (32, 8192, 64)
  float* attn = (float*)d_out + (size_t)32 * WTOT * WS;         // (4096, 64, 64)
  win_attn<<<dim3(4096), dim3(256), 0, stream>>>(q, k, v, table, xout, attn);
}